// Round 8
// baseline (449.172 us; speedup 1.0000x reference)
//
#include <hip/hip_runtime.h>
#include <hip/hip_bf16.h>

// Scaled dot-product attention, B=2 H=12 S=2048 D=64, fp32 in/out.
// Outputs: out [B,H,S,D] then we [B,H,S,S] concatenated in d_out.
// R7: barrier-free redesign. No K/V LDS staging (L2-resident; direct
// global fragment loads). Block = 256 thr = 4 waves = 4 t-quarters of ONE
// 16-row q-tile; grid 3072 (12 blocks/CU -> up to 32 waves/CU). Exactly
// 2 block barriers (denominator table, PV combine). Per-wave-private
// p_sh bounce (validated R2). HW bf16 cvt.

typedef short          s16x8 __attribute__((ext_vector_type(8)));
typedef unsigned short u16x8 __attribute__((ext_vector_type(8)));
typedef float          f32x4 __attribute__((ext_vector_type(4)));

#define kS   2048
#define kD   64
#define kBH  24
#define kTQ  512                     // per-wave t-quarter
#define OUT_ELEMS (kBH * kS * kD)    // 3145728

static __device__ __forceinline__ unsigned short f2bf(float f) {
    __hip_bfloat16 h = __float2bfloat16(f);   // RNE, packs to v_cvt_pk_bf16_f32
    return *reinterpret_cast<unsigned short*>(&h);
}

// 8 consecutive fp32 -> bf16x8 fragment
static __device__ __forceinline__ s16x8 ld8bf(const float* p) {
    float4 a = *(const float4*)p;
    float4 b = *(const float4*)(p + 4);
    union { u16x8 u; s16x8 s; } t;
    t.u[0] = f2bf(a.x); t.u[1] = f2bf(a.y); t.u[2] = f2bf(a.z); t.u[3] = f2bf(a.w);
    t.u[4] = f2bf(b.x); t.u[5] = f2bf(b.y); t.u[6] = f2bf(b.z); t.u[7] = f2bf(b.w);
    return t.s;
}

__global__ __launch_bounds__(256, 6)
void attn_fused(const float* __restrict__ Qg, const float* __restrict__ Kg,
                const float* __restrict__ Vg, const float* __restrict__ Mg,
                float* __restrict__ Og, float* __restrict__ Wg)
{
    __shared__ float sm_sh[4][16];                       // per-wave denom partials
    __shared__ __align__(16) float oacc[3][64 * 16];     // PV partials, waves 1..3
    __shared__ __align__(16) unsigned short p_sh[4][16 * 40];

    const int tid  = threadIdx.x;
    const int wv   = tid >> 6;
    const int lane = tid & 63;
    const int g    = lane >> 4;
    const int c    = lane & 15;

    // XCD swizzle: 3072 blocks, 384/XCD = 3 whole heads per XCD
    const int wg = ((int)blockIdx.x & 7) * 384 + ((int)blockIdx.x >> 3);
    const int bh = wg >> 7;
    const int q0 = (wg & 127) * 16;
    const int tq = wv * kTQ;

    // ---- Q A-frags: row q0+c, k = h*32 + g*8 + j (validated R2) ----
    const float* qp = Qg + ((size_t)(bh * kS + q0 + c)) * kD + g * 8;
    s16x8 aQ[2];
    aQ[0] = ld8bf(qp);
    aQ[1] = ld8bf(qp + 32);

    const float* Kbh  = Kg + (size_t)bh * kS * kD;
    const float* Vbh  = Vg + (size_t)bh * kS * kD;
    const float* mrow = Mg + (size_t)(q0 + g * 4) * kS;

    // ================= pass 1: partial denominators =================
    float sm[4] = {0.f, 0.f, 0.f, 0.f};
    for (int t0 = tq; t0 < tq + kTQ; t0 += 32) {
        #pragma unroll
        for (int tt = 0; tt < 2; ++tt) {
            const float* kp = Kbh + (size_t)(t0 + tt * 16 + c) * kD + g * 8;
            f32x4 acc = {0.f, 0.f, 0.f, 0.f};
            acc = __builtin_amdgcn_mfma_f32_16x16x32_bf16(aQ[0], ld8bf(kp),      acc, 0, 0, 0);
            acc = __builtin_amdgcn_mfma_f32_16x16x32_bf16(aQ[1], ld8bf(kp + 32), acc, 0, 0, 0);
            const int t = t0 + tt * 16 + c;
            #pragma unroll
            for (int j = 0; j < 4; ++j)
                sm[j] += __expf(acc[j] * 0.125f + mrow[(size_t)j * kS + t]);
        }
    }
    #pragma unroll
    for (int j = 0; j < 4; ++j) {   // reduce over 16 column-lanes
        float s = sm[j];
        s += __shfl_xor(s, 1);
        s += __shfl_xor(s, 2);
        s += __shfl_xor(s, 4);
        s += __shfl_xor(s, 8);
        sm[j] = s;
    }
    if (c == 0) {
        #pragma unroll
        for (int j = 0; j < 4; ++j) sm_sh[wv][g * 4 + j] = sm[j];
    }
    __syncthreads();                                     // barrier #1
    float sminv[4];
    #pragma unroll
    for (int j = 0; j < 4; ++j)
        sminv[j] = 1.0f / (sm_sh[0][g * 4 + j] + sm_sh[1][g * 4 + j] +
                           sm_sh[2][g * 4 + j] + sm_sh[3][g * 4 + j]);

    // ================= pass 2: write we, accumulate PV =================
    f32x4 accO[4];
    #pragma unroll
    for (int dt = 0; dt < 4; ++dt) accO[dt] = f32x4{0.f, 0.f, 0.f, 0.f};

    float* wrow = Wg + ((size_t)(bh * kS + q0 + g * 4)) * kS;
    unsigned short* p_shw = p_sh[wv];

    for (int t0 = tq; t0 < tq + kTQ; t0 += 32) {
        #pragma unroll
        for (int tt = 0; tt < 2; ++tt) {
            const float* kp = Kbh + (size_t)(t0 + tt * 16 + c) * kD + g * 8;
            f32x4 acc = {0.f, 0.f, 0.f, 0.f};
            acc = __builtin_amdgcn_mfma_f32_16x16x32_bf16(aQ[0], ld8bf(kp),      acc, 0, 0, 0);
            acc = __builtin_amdgcn_mfma_f32_16x16x32_bf16(aQ[1], ld8bf(kp + 32), acc, 0, 0, 0);
            const int t = t0 + tt * 16 + c;
            #pragma unroll
            for (int j = 0; j < 4; ++j) {
                const float p = __expf(acc[j] * 0.125f + mrow[(size_t)j * kS + t]) * sminv[j];
                __builtin_nontemporal_store(p, wrow + (size_t)j * kS + t);
                p_shw[(g * 4 + j) * 40 + tt * 16 + c] = f2bf(p);
            }
        }

        // A-frag of P: row c, k = g*8+j (validated R2; per-wave LDS, no barrier)
        s16x8 pa = *(const s16x8*)((const char*)p_shw + c * 80 + g * 16);

        // B-frags of V direct from global: bV[j] = V[t0+8g+j][16dt+c]
        const float* vb = Vbh + (size_t)(t0 + g * 8) * kD + c;
        #pragma unroll
        for (int dt = 0; dt < 4; ++dt) {
            union { u16x8 u; s16x8 s; } bv;
            #pragma unroll
            for (int j = 0; j < 8; ++j)
                bv.u[j] = f2bf(vb[(size_t)j * kD + dt * 16]);
            accO[dt] = __builtin_amdgcn_mfma_f32_16x16x32_bf16(pa, bv.s, accO[dt], 0, 0, 0);
        }
    }

    // ===== epilogue: combine the 4 t-quarter PV partials =====
    if (wv != 0) {
        float* dst = &oacc[wv - 1][lane * 16];
        #pragma unroll
        for (int dt = 0; dt < 4; ++dt)
            #pragma unroll
            for (int j = 0; j < 4; ++j) dst[dt * 4 + j] = accO[dt][j];
    }
    __syncthreads();                                     // barrier #2
    if (wv == 0) {
        #pragma unroll
        for (int w = 0; w < 3; ++w)
            #pragma unroll
            for (int dt = 0; dt < 4; ++dt)
                #pragma unroll
                for (int j = 0; j < 4; ++j)
                    accO[dt][j] += oacc[w][lane * 16 + dt * 4 + j];
        float* orow = Og + ((size_t)(bh * kS + q0 + g * 4)) * kD + c;
        #pragma unroll
        for (int dt = 0; dt < 4; ++dt)
            #pragma unroll
            for (int j = 0; j < 4; ++j)
                __builtin_nontemporal_store(accO[dt][j], orow + (size_t)j * kD + dt * 16);
    }
}

extern "C" void kernel_launch(void* const* d_in, const int* in_sizes, int n_in,
                              void* d_out, int out_size, void* d_ws, size_t ws_size,
                              hipStream_t stream) {
    const float* q = (const float*)d_in[0];
    const float* k = (const float*)d_in[1];
    const float* v = (const float*)d_in[2];
    const float* m = (const float*)d_in[3];
    float* out = (float*)d_out;
    float* we  = out + OUT_ELEMS;
    attn_fused<<<dim3(kBH * 128), dim3(256), 0, stream>>>(q, k, v, m, out, we);
}

// Round 9
// 163.105 us; speedup vs baseline: 2.7539x; 2.7539x over previous
//
#include <hip/hip_runtime.h>

// Scaled dot-product attention, B=2 H=12 S=2048 D=64, fp32 in/out.
// Outputs: out [B,H,S,D] then we [B,H,S,S] concatenated in d_out.
// R8 = R2 verbatim (best: 171.5us) + double-buffered LDS with issue-early
// prefetch (1 barrier/tile instead of 2; loads in flight across compute)
// + vt_sh XOR swizzle (neutral-to-positive per R4/R6 controls).
// All fragment/mask/store lane mappings byte-identical to validated R2.

typedef short          s16x8 __attribute__((ext_vector_type(8)));
typedef unsigned short u16x8 __attribute__((ext_vector_type(8)));
typedef float          f32x4 __attribute__((ext_vector_type(4)));

#define kS   2048
#define kD   64
#define kBH  24
#define OUT_ELEMS (kBH * kS * kD)   // 3145728

static __device__ __forceinline__ unsigned short f2bf(float f) {
    union { float f; unsigned u; } x; x.f = f;
    return (unsigned short)((x.u + 0x7fffu + ((x.u >> 16) & 1u)) >> 16); // RNE
}

static __device__ __forceinline__ u16x8 cvt8(const float4 f0, const float4 f1) {
    u16x8 r;
    r[0] = f2bf(f0.x); r[1] = f2bf(f0.y); r[2] = f2bf(f0.z); r[3] = f2bf(f0.w);
    r[4] = f2bf(f1.x); r[5] = f2bf(f1.y); r[6] = f2bf(f1.z); r[7] = f2bf(f1.w);
    return r;
}

__global__ __launch_bounds__(256)
void attn_fused(const float* __restrict__ Qg, const float* __restrict__ Kg,
                const float* __restrict__ Vg, const float* __restrict__ Mg,
                float* __restrict__ Og, float* __restrict__ Wg)
{
    // K tile [32 t][64 d] bf16, XOR-swizzled: byte ^= (row&7)<<4   (x2 dbuf)
    __shared__ __align__(16) unsigned short k_sh[2][32 * 64];
    // V^T tile [64 d][32 t] bf16, XOR-swizzled: byte ^= ((d>>3)&7)<<4 (x2)
    __shared__ __align__(16) unsigned short vt_sh[2][64 * 32];
    // per-wave P tile [16 q][40 t-pad] bf16
    __shared__ __align__(16) unsigned short p_sh[4][16 * 40];

    const int tid  = threadIdx.x;
    const int wv   = tid >> 6;
    const int lane = tid & 63;
    const int g    = lane >> 4;   // 0..3
    const int c    = lane & 15;   // 0..15

    // XCD-bijective swizzle: 768 blocks, 96/XCD => each XCD owns 3 whole heads
    const int wg = ((int)blockIdx.x & 7) * 96 + ((int)blockIdx.x >> 3);
    const int bh = wg >> 5;
    const int qb = wg & 31;
    const int q0 = qb * 64 + wv * 16;

    // ---- Q A-fragments (row = q0+c, k = h*32+g*8+j), validated R2 ----
    s16x8 aQ[2];
    {
        const float* qp = Qg + ((size_t)(bh * kS + q0 + c)) * kD + g * 8;
        #pragma unroll
        for (int h = 0; h < 2; ++h) {
            float4 f0 = *(const float4*)(qp + h * 32);
            float4 f1 = *(const float4*)(qp + h * 32 + 4);
            union { u16x8 u; s16x8 s; } t; t.u = cvt8(f0, f1);
            aQ[h] = t.s;
        }
    }

    // staging: thread -> (row sr, cols sc..sc+7) of the 32x64 fp32 tile
    const int sr = tid >> 3;
    const int sc = (tid & 7) * 8;
    const float* kstage = Kg + ((size_t)bh * kS + sr) * kD + sc;
    const float* vstage = Vg + ((size_t)bh * kS + sr) * kD + sc;
    const unsigned kaddr_w = (unsigned)((sr * 128 + sc * 2) ^ ((sr & 7) << 4));
    const float* mrow = Mg + (size_t)(q0 + g * 4) * kS;   // R2 mask mapping

    // ================= pass 1: softmax denominators =================
    {
        *(u16x8*)((char*)k_sh[0] + kaddr_w) = cvt8(*(const float4*)kstage, *(const float4*)(kstage + 4));
    }
    __syncthreads();

    float sm[4] = {0.f, 0.f, 0.f, 0.f};
    int cur = 0;
    for (int t0 = 0; t0 < kS; t0 += 32) {
        const bool nxt = (t0 + 32) < kS;
        float4 kf0, kf1;
        if (nxt) {   // issue-early: load stays in flight across the MFMA+exp
            const float* src = kstage + (size_t)(t0 + 32) * kD;
            kf0 = *(const float4*)src; kf1 = *(const float4*)(src + 4);
        }
        #pragma unroll
        for (int tt = 0; tt < 2; ++tt) {
            const int row = tt * 16 + c;
            f32x4 acc = {0.f, 0.f, 0.f, 0.f};
            #pragma unroll
            for (int h = 0; h < 2; ++h) {
                const unsigned a = (unsigned)((row * 128 + h * 64 + g * 16) ^ ((row & 7) << 4));
                s16x8 bK = *(const s16x8*)((const char*)k_sh[cur] + a);
                acc = __builtin_amdgcn_mfma_f32_16x16x32_bf16(aQ[h], bK, acc, 0, 0, 0);
            }
            const int t = t0 + tt * 16 + c;
            #pragma unroll
            for (int j = 0; j < 4; ++j)
                sm[j] += __expf(acc[j] * 0.125f + mrow[(size_t)j * kS + t]);
        }
        if (nxt) {
            *(u16x8*)((char*)k_sh[cur ^ 1] + kaddr_w) = cvt8(kf0, kf1);
            __syncthreads();
            cur ^= 1;
        }
    }
    #pragma unroll
    for (int j = 0; j < 4; ++j) {   // reduce over the 16 column-lanes
        float s = sm[j];
        s += __shfl_xor(s, 1);
        s += __shfl_xor(s, 2);
        s += __shfl_xor(s, 4);
        s += __shfl_xor(s, 8);
        sm[j] = 1.0f / s;
    }

    // ================= pass 2: write we, accumulate PV =================
    f32x4 accO[4];
    #pragma unroll
    for (int dt = 0; dt < 4; ++dt) accO[dt] = f32x4{0.f, 0.f, 0.f, 0.f};

    float* wrow = Wg + ((size_t)(bh * kS + q0 + g * 4)) * kS;

    __syncthreads();   // pass1 reads of k_sh complete before restage
    {
        *(u16x8*)((char*)k_sh[0] + kaddr_w) = cvt8(*(const float4*)kstage, *(const float4*)(kstage + 4));
        u16x8 vb = cvt8(*(const float4*)vstage, *(const float4*)(vstage + 4));
        #pragma unroll
        for (int i = 0; i < 8; ++i) {
            const int d = sc + i;
            const unsigned b = (unsigned)((d * 64 + sr * 2) ^ (((d >> 3) & 7) << 4));
            *(unsigned short*)((char*)vt_sh[0] + b) = vb[i];
        }
    }
    __syncthreads();

    cur = 0;
    for (int t0 = 0; t0 < kS; t0 += 32) {
        const bool nxt = (t0 + 32) < kS;
        float4 kf0, kf1, vf0, vf1;
        if (nxt) {
            const float* srck = kstage + (size_t)(t0 + 32) * kD;
            kf0 = *(const float4*)srck; kf1 = *(const float4*)(srck + 4);
            const float* srcv = vstage + (size_t)(t0 + 32) * kD;
            vf0 = *(const float4*)srcv; vf1 = *(const float4*)(srcv + 4);
        }

        #pragma unroll
        for (int tt = 0; tt < 2; ++tt) {
            const int row = tt * 16 + c;
            f32x4 acc = {0.f, 0.f, 0.f, 0.f};
            #pragma unroll
            for (int h = 0; h < 2; ++h) {
                const unsigned a = (unsigned)((row * 128 + h * 64 + g * 16) ^ ((row & 7) << 4));
                s16x8 bK = *(const s16x8*)((const char*)k_sh[cur] + a);
                acc = __builtin_amdgcn_mfma_f32_16x16x32_bf16(aQ[h], bK, acc, 0, 0, 0);
            }
            const int t = t0 + tt * 16 + c;
            #pragma unroll
            for (int j = 0; j < 4; ++j) {
                const float p = __expf(acc[j] * 0.125f + mrow[(size_t)j * kS + t]) * sm[j];
                __builtin_nontemporal_store(p, wrow + (size_t)j * kS + t);   // R2 store pattern
                p_sh[wv][(g * 4 + j) * 40 + tt * 16 + c] = f2bf(p);
            }
        }

        // A-frag of P: row=c, k=g*8+j (validated R2)
        s16x8 pa = *(const s16x8*)((const char*)&p_sh[wv][0] + c * 80 + g * 16);
        #pragma unroll
        for (int dt = 0; dt < 4; ++dt) {
            const int d = dt * 16 + c;
            const unsigned b = (unsigned)((d * 64 + g * 16) ^ (((d >> 3) & 7) << 4));
            s16x8 bV = *(const s16x8*)((const char*)vt_sh[cur] + b);
            accO[dt] = __builtin_amdgcn_mfma_f32_16x16x32_bf16(pa, bV, accO[dt], 0, 0, 0);
        }

        if (nxt) {
            *(u16x8*)((char*)k_sh[cur ^ 1] + kaddr_w) = cvt8(kf0, kf1);
            u16x8 vb = cvt8(vf0, vf1);
            #pragma unroll
            for (int i = 0; i < 8; ++i) {
                const int d = sc + i;
                const unsigned b = (unsigned)((d * 64 + sr * 2) ^ (((d >> 3) & 7) << 4));
                *(unsigned short*)((char*)vt_sh[cur ^ 1] + b) = vb[i];
            }
            __syncthreads();
            cur ^= 1;
        }
    }

    // ---- epilogue: out[bh][q0+g*4+j][dt*16+c] (validated R2) ----
    float* orow = Og + ((size_t)(bh * kS + q0 + g * 4)) * kD + c;
    #pragma unroll
    for (int dt = 0; dt < 4; ++dt) {
        #pragma unroll
        for (int j = 0; j < 4; ++j)
            __builtin_nontemporal_store(accO[dt][j], orow + (size_t)j * kD + dt * 16);
    }
}

extern "C" void kernel_launch(void* const* d_in, const int* in_sizes, int n_in,
                              void* d_out, int out_size, void* d_ws, size_t ws_size,
                              hipStream_t stream) {
    const float* q = (const float*)d_in[0];
    const float* k = (const float*)d_in[1];
    const float* v = (const float*)d_in[2];
    const float* m = (const float*)d_in[3];
    float* out = (float*)d_out;
    float* we  = out + OUT_ELEMS;
    attn_fused<<<dim3(kBH * 32), dim3(256), 0, stream>>>(q, k, v, m, out, we);
}